// Round 2
// baseline (1848.001 us; speedup 1.0000x reference)
//
#include <hip/hip_runtime.h>
#include <hip/hip_bf16.h>
#include <cstdint>
#include <cstddef>

using bf16 = __hip_bfloat16;

typedef __attribute__((ext_vector_type(4))) float f32x4;
typedef __attribute__((ext_vector_type(8))) short s16x8;

__device__ __forceinline__ bf16 to_bf16(float v) { return __float2bfloat16(v); }

struct alignas(8) bf16x4_pack { bf16 x, y, z, w; };

// bijective XCD-chunking swizzle (m204): XCD k gets a contiguous fid range
__device__ __forceinline__ int xcd_swz(int orig, int nwg) {
    int xcd = orig & 7, base = orig >> 3;
    int q = nwg >> 3, r = nwg & 7;
    return (xcd < r ? xcd * (q + 1) : r * (q + 1) + (xcd - r) * q) + base;
}

// ---------------- fp32 -> bf16 elementwise (float4 vectorized) ----------------
__global__ void k_conv_f32_bf16(const float* __restrict__ in, bf16* __restrict__ out, int n4) {
    int i = blockIdx.x * blockDim.x + threadIdx.x;
    if (i >= n4) return;
    float4 v = ((const float4*)in)[i];
    bf16x4_pack o{to_bf16(v.x), to_bf16(v.y), to_bf16(v.z), to_bf16(v.w)};
    ((bf16x4_pack*)out)[i] = o;
}

// ---------------- fp32 [K][N] -> bf16 [N][K] tiled transpose ----------------
__global__ __launch_bounds__(256) void k_transpose_f32_bf16(
    const float* __restrict__ in, bf16* __restrict__ out,
    int K, int N, long inz, long outz)
{
    __shared__ float t[32][33];
    in  += (long)blockIdx.z * inz;
    out += (long)blockIdx.z * outz;
    int n0 = blockIdx.x * 32, k0 = blockIdx.y * 32;
    int tx = threadIdx.x & 31, ty = threadIdx.x >> 5;   // 32x8
#pragma unroll
    for (int r = 0; r < 32; r += 8)
        t[ty + r][tx] = in[(long)(k0 + ty + r) * N + (n0 + tx)];
    __syncthreads();
#pragma unroll
    for (int r = 0; r < 32; r += 8)
        out[(long)(n0 + ty + r) * K + (k0 + tx)] = to_bf16(t[tx][ty + r]);
}

// ---------------- async global->LDS 16B helper ----------------
__device__ __forceinline__ void gload_lds16(const void* g, void* l) {
    __builtin_amdgcn_global_load_lds(
        (const __attribute__((address_space(1))) void*)g,
        (__attribute__((address_space(3))) void*)l,
        16, 0, 0);
}

// ---------------- main bf16 MFMA GEMM: C = act(A[M,K] * W^T[N,K] + bias) ----------------
// 128x128 tile, BK=32, 4 waves (2x2 of 64x64), m97-style global_load_lds staging.
// A is [M][1024] (lda fixed = 1024); SEG=1 reads the virtual concat [A0|A1|A2] along K.
// Grid: 1D x = nM*nN tiles, M-major within XCD-chunked fid (W-slab L2 reuse).
template<int ACT, int SEG>   // ACT: 0 = none, 1 = relu, 2 = silu
__global__ __launch_bounds__(256) void k_gemm(
    const bf16* __restrict__ A0, const bf16* __restrict__ A1, const bf16* __restrict__ A2,
    long az,
    const bf16* __restrict__ W, long wz,        // W is [N][K] row-major
    const float* __restrict__ bias, long bz,
    float* __restrict__ Cf, int ldcf, long cfz,
    bf16* __restrict__ Cb, int ldcb, long cbz,
    int K, int nM)
{
    __shared__ bf16 As[128 * 32];
    __shared__ bf16 Bs[128 * 32];
    const int tid  = threadIdx.x;
    const int wid  = tid >> 6;
    const int lane = tid & 63;
    const int z  = blockIdx.z;

    const int fid = xcd_swz(blockIdx.x, gridDim.x);
    const int m0 = (fid % nM) * 128;
    const int n0 = (fid / nM) * 128;

    // staging: thread t -> row t/4, col-elem (t%4)*8 (byte t*16 in LDS, linear)
    const int srow = tid >> 2;
    const int scol = (tid & 3) * 8;
    const long arow = (long)(m0 + srow) * 1024 + scol;
    const bf16* a0 = A0 + (long)z * az + arow;
    const bf16* a1 = SEG ? (A1 + arow) : nullptr;
    const bf16* a2 = SEG ? (A2 + arow) : nullptr;
    const bf16* bg = W + (long)z * wz + (long)(n0 + srow) * K + scol;

    char* asb = (char*)As;
    char* bsb = (char*)Bs;

    f32x4 acc[4][4] = {};

    const int wm = (wid >> 1) * 64;
    const int wn = (wid & 1) * 64;
    const int fr = lane & 15;         // fragment row (A) / col (B)
    const int kq = (lane >> 4) * 8;   // k offset within BK

    for (int k0 = 0; k0 < K; k0 += 32) {
        const bf16* ap;
        if (SEG) {
            const int seg = k0 >> 10, ko = k0 & 1023;
            ap = (seg == 0 ? a0 : (seg == 1 ? a1 : a2)) + ko;
        } else {
            ap = a0 + k0;
        }
        const bf16* bp = bg + k0;

        __syncthreads();   // previous iter's LDS reads done before overwrite
        gload_lds16(ap,                 asb + wid * 1024);
        gload_lds16(ap + 64 * 1024,     asb + 4096 + wid * 1024);
        gload_lds16(bp,                 bsb + wid * 1024);
        gload_lds16(bp + (long)64 * K,  bsb + 4096 + wid * 1024);
        __syncthreads();   // drains vmcnt -> tiles resident

        s16x8 af[4], bfv[4];
#pragma unroll
        for (int i = 0; i < 4; ++i)
            af[i] = *(const s16x8*)(As + (wm + i * 16 + fr) * 32 + kq);
#pragma unroll
        for (int i = 0; i < 4; ++i)
            bfv[i] = *(const s16x8*)(Bs + (wn + i * 16 + fr) * 32 + kq);
#pragma unroll
        for (int mi = 0; mi < 4; ++mi)
#pragma unroll
            for (int ni = 0; ni < 4; ++ni)
                acc[mi][ni] = __builtin_amdgcn_mfma_f32_16x16x32_bf16(
                    af[mi], bfv[ni], acc[mi][ni], 0, 0, 0);
    }

    // epilogue: C/D layout col = lane&15, row = (lane>>4)*4 + reg
    const int rb = (lane >> 4) * 4;
#pragma unroll
    for (int ni = 0; ni < 4; ++ni) {
        const int col = n0 + wn + ni * 16 + fr;
        const float bv = bias ? bias[(long)z * bz + col] : 0.f;
#pragma unroll
        for (int mi = 0; mi < 4; ++mi) {
#pragma unroll
            for (int r = 0; r < 4; ++r) {
                const int row = m0 + wm + mi * 16 + rb + r;
                float v = acc[mi][ni][r] + bv;
                if (ACT == 1) v = fmaxf(v, 0.f);
                if (ACT == 2) v = v / (1.f + __expf(-v));
                if (Cf) Cf[(long)z * cfz + (long)row * ldcf + col] = v;
                if (Cb) Cb[(long)z * cbz + (long)row * ldcb + col] = to_bf16(v);
            }
        }
    }
}

// ---------------- fused mask head: logits = t @ md_W2 + b2 ; softmax over E=16 ----------------
__global__ __launch_bounds__(64) void k_mask_softmax(
    const bf16* __restrict__ t, const float* __restrict__ W2,
    const float* __restrict__ b2, float* __restrict__ mask_out)
{
    const int tok = blockIdx.x;
    const int lane = threadIdx.x;
    float part[16];
#pragma unroll
    for (int e = 0; e < 16; ++e) part[e] = 0.f;
    const bf16* tr = t + (long)tok * 1024 + lane * 16;
#pragma unroll
    for (int kk = 0; kk < 16; ++kk) {
        float x = __bfloat162float(tr[kk]);
        const float* wr = W2 + (long)(lane * 16 + kk) * 16;
#pragma unroll
        for (int e = 0; e < 16; ++e) part[e] += x * wr[e];
    }
#pragma unroll
    for (int e = 0; e < 16; ++e) {
#pragma unroll
        for (int off = 32; off >= 1; off >>= 1)
            part[e] += __shfl_down(part[e], off);
    }
    if (lane == 0) {
        float vals[16], mx = -1e30f;
#pragma unroll
        for (int e = 0; e < 16; ++e) { vals[e] = part[e] + b2[e]; mx = fmaxf(mx, vals[e]); }
        float s = 0.f;
#pragma unroll
        for (int e = 0; e < 16; ++e) { vals[e] = __expf(vals[e] - mx); s += vals[e]; }
        float inv = 1.f / s;
#pragma unroll
        for (int e = 0; e < 16; ++e) mask_out[tok * 16 + e] = vals[e] * inv;
    }
}

// ---------------- qk = sum_e mask[tok][e] * EO[tok][e][:] -> bf16 ----------------
__global__ void k_qk(const float* __restrict__ EO, const float* __restrict__ mask,
                     bf16* __restrict__ qkb)
{
    int i = blockIdx.x * blockDim.x + threadIdx.x;    // unit = 4 d's
    int tok = i >> 8;
    int d4  = (i & 255) << 2;
    const float* eo = EO + (long)tok * 16384 + d4;
    const float* mk = mask + tok * 16;
    float4 s = make_float4(0.f, 0.f, 0.f, 0.f);
#pragma unroll
    for (int e = 0; e < 16; ++e) {
        float m = mk[e];
        float4 v = *(const float4*)(eo + e * 1024);
        s.x += m * v.x; s.y += m * v.y; s.z += m * v.z; s.w += m * v.w;
    }
    bf16x4_pack o{to_bf16(s.x), to_bf16(s.y), to_bf16(s.z), to_bf16(s.w)};
    ((bf16x4_pack*)qkb)[i] = o;
}

extern "C" void kernel_launch(void* const* d_in, const int* in_sizes, int n_in,
                              void* d_out, int out_size, void* d_ws, size_t ws_size,
                              hipStream_t stream)
{
    const int Mtok = 4096, D = 1024, E = 16, V = 32000, DIN = 3072;

    const float* L      = (const float*)d_in[0];
    const float* mL     = (const float*)d_in[1];
    const float* prompt = (const float*)d_in[2];
    const float* noise  = (const float*)d_in[3];
    const float* qa_W1 = (const float*)d_in[4];  const float* qa_b1 = (const float*)d_in[5];
    const float* qa_W2 = (const float*)d_in[6];  const float* qa_b2 = (const float*)d_in[7];
    const float* qb_W1 = (const float*)d_in[8];  const float* qb_b1 = (const float*)d_in[9];
    const float* qb_W2 = (const float*)d_in[10]; const float* qb_b2 = (const float*)d_in[11];
    const float* qc_W1 = (const float*)d_in[12]; const float* qc_b1 = (const float*)d_in[13];
    const float* qc_W2 = (const float*)d_in[14]; const float* qc_b2 = (const float*)d_in[15];
    const float* ek_W1 = (const float*)d_in[16]; const float* ek_b1 = (const float*)d_in[17];
    const float* ek_W2 = (const float*)d_in[18]; const float* ek_b2 = (const float*)d_in[19];
    const float* md_W1 = (const float*)d_in[20]; const float* md_b1 = (const float*)d_in[21];
    const float* md_W2 = (const float*)d_in[22]; const float* md_b2 = (const float*)d_in[23];
    const float* td_W  = (const float*)d_in[24]; const float* td_b  = (const float*)d_in[25];

    float* out = (float*)d_out;
    float* out_L2   = out;                       // [4096,1024]
    float* out_mLp  = out + 4194304;             // [4096,1024]
    float* out_mask = out + 8388608;             // [4096,16]
    float* out_txt  = out + 8454144;             // [4096,32000]
    float* out_EO   = out + 139526144;           // [4096,16,1024]

    char* ws = (char*)d_ws;
    size_t off = 0;
    auto alloc = [&](size_t bytes) -> void* {
        void* p = ws + off;
        off += (bytes + 255) & ~(size_t)255;
        return p;
    };

    bf16* wqa1 = (bf16*)alloc((size_t)DIN * D * 2);
    bf16* wqa2 = (bf16*)alloc((size_t)D * D * 2);
    bf16* wqb1 = (bf16*)alloc((size_t)DIN * D * 2);
    bf16* wqb2 = (bf16*)alloc((size_t)D * D * 2);
    bf16* wqc1 = (bf16*)alloc((size_t)DIN * D * 2);
    bf16* wqc2 = (bf16*)alloc((size_t)D * D * 2);
    bf16* wmd1 = (bf16*)alloc((size_t)D * D * 2);
    bf16* wek1 = (bf16*)alloc((size_t)E * D * D * 2);
    bf16* wek2 = (bf16*)alloc((size_t)E * D * D * 2);
    bf16* wtd  = (bf16*)alloc((size_t)D * V * 2);

    bf16* Lb   = (bf16*)alloc((size_t)Mtok * D * 2);
    bf16* mLb  = (bf16*)alloc((size_t)Mtok * D * 2);
    bf16* Pb   = (bf16*)alloc((size_t)Mtok * D * 2);
    bf16* Nb   = (bf16*)alloc((size_t)Mtok * D * 2);
    bf16* hbuf = (bf16*)alloc((size_t)Mtok * D * 2);
    bf16* L1b  = (bf16*)alloc((size_t)Mtok * D * 2);
    bf16* sLb  = (bf16*)alloc((size_t)Mtok * D * 2);
    bf16* tb   = (bf16*)alloc((size_t)Mtok * D * 2);
    bf16* qkb  = (bf16*)alloc((size_t)Mtok * D * 2);
    bf16* L2b  = (bf16*)alloc((size_t)Mtok * D * 2);

    const size_t hall_bytes = (size_t)E * Mtok * D * 2;
    bool batched = (off + hall_bytes + 256 <= ws_size);
    bf16* hall = batched ? (bf16*)alloc(hall_bytes) : nullptr;

    // --- activation conversions ---
    auto conv = [&](const float* src, bf16* dst, long n) {
        int n4 = (int)(n / 4);
        k_conv_f32_bf16<<<dim3((n4 + 255) / 256), dim3(256), 0, stream>>>(src, dst, n4);
    };
    conv(L, Lb, (long)Mtok * D);
    conv(mL, mLb, (long)Mtok * D);
    conv(prompt, Pb, (long)Mtok * D);
    conv(noise, Nb, (long)Mtok * D);

    // --- weight transpose+convert: [K][N] fp32 -> [N][K] bf16 ---
    auto transp = [&](const float* src, bf16* dst, int K, int N, int Z, long inz, long outz) {
        dim3 g(N / 32, K / 32, Z);
        k_transpose_f32_bf16<<<g, dim3(256), 0, stream>>>(src, dst, K, N, inz, outz);
    };
    transp(qa_W1, wqa1, DIN, D, 1, 0, 0);
    transp(qa_W2, wqa2, D, D, 1, 0, 0);
    transp(qb_W1, wqb1, DIN, D, 1, 0, 0);
    transp(qb_W2, wqb2, D, D, 1, 0, 0);
    transp(qc_W1, wqc1, DIN, D, 1, 0, 0);
    transp(qc_W2, wqc2, D, D, 1, 0, 0);
    transp(md_W1, wmd1, D, D, 1, 0, 0);
    transp(ek_W1, wek1, D, D, 16, (long)D * D, (long)D * D);
    transp(ek_W2, wek2, D, D, 16, (long)D * D, (long)D * D);
    transp(td_W,  wtd,  D, V, 1, 0, 0);

    // --- GEMM dispatch: A = [A0|A1|A2] along K if seg, else A0. ---
    auto gemm = [&](int ACT, bool seg,
                    const bf16* A0, const bf16* A1, const bf16* A2, long az,
                    const bf16* Wt, long wz, const float* bias, long bz,
                    float* Cf, int ldcf, long cfz, bf16* Cb, int ldcb, long cbz,
                    int M, int N, int K, int Z) {
        int nM = M / 128, nN = N / 128;
        dim3 g(nM * nN, 1, Z);
        dim3 b(256);
        if (seg) {
            if (ACT == 1)
                k_gemm<1, 1><<<g, b, 0, stream>>>(A0, A1, A2, az, Wt, wz, bias, bz, Cf, ldcf, cfz, Cb, ldcb, cbz, K, nM);
            else
                k_gemm<0, 1><<<g, b, 0, stream>>>(A0, A1, A2, az, Wt, wz, bias, bz, Cf, ldcf, cfz, Cb, ldcb, cbz, K, nM);
        } else {
            if (ACT == 0)
                k_gemm<0, 0><<<g, b, 0, stream>>>(A0, A0, A0, az, Wt, wz, bias, bz, Cf, ldcf, cfz, Cb, ldcb, cbz, K, nM);
            else if (ACT == 1)
                k_gemm<1, 0><<<g, b, 0, stream>>>(A0, A0, A0, az, Wt, wz, bias, bz, Cf, ldcf, cfz, Cb, ldcb, cbz, K, nM);
            else
                k_gemm<2, 0><<<g, b, 0, stream>>>(A0, A0, A0, az, Wt, wz, bias, bz, Cf, ldcf, cfz, Cb, ldcb, cbz, K, nM);
        }
    };

    // L1 = qa([L | prompt | mL])
    gemm(1, true, Lb, Pb, mLb, 0, wqa1, 0, qa_b1, 0, nullptr, 0, 0, hbuf, D, 0, Mtok, D, DIN, 1);
    gemm(0, false, hbuf, 0, 0, 0, wqa2, 0, qa_b2, 0, nullptr, 0, 0, L1b, D, 0, Mtok, D, D, 1);

    // sL = qb([noise | prompt | L1])
    gemm(1, true, Nb, Pb, L1b, 0, wqb1, 0, qb_b1, 0, nullptr, 0, 0, hbuf, D, 0, Mtok, D, DIN, 1);
    gemm(0, false, hbuf, 0, 0, 0, wqb2, 0, qb_b2, 0, nullptr, 0, 0, sLb, D, 0, Mtok, D, D, 1);

    // mask = softmax(relu(sL @ md_W1 + b1) @ md_W2 + b2)
    gemm(1, false, sLb, 0, 0, 0, wmd1, 0, md_b1, 0, nullptr, 0, 0, tb, D, 0, Mtok, D, D, 1);
    k_mask_softmax<<<dim3(Mtok), dim3(64), 0, stream>>>(tb, md_W2, md_b2, out_mask);

    // experts: EO[tok][e][:] = silu(L1 @ W1[e] + b1[e]) @ W2[e] + b2[e]
    if (batched) {
        gemm(2, false, L1b, 0, 0, 0, wek1, (long)D * D, ek_b1, D, nullptr, 0, 0,
             hall, D, (long)Mtok * D, Mtok, D, D, 16);
        gemm(0, false, hall, 0, 0, (long)Mtok * D, wek2, (long)D * D, ek_b2, D,
             out_EO, E * D, D, nullptr, 0, 0, Mtok, D, D, 16);
    } else {
        for (int e = 0; e < 16; ++e) {
            gemm(2, false, L1b, 0, 0, 0, wek1 + (size_t)e * D * D, 0, ek_b1 + e * D, 0,
                 nullptr, 0, 0, hbuf, D, 0, Mtok, D, D, 1);
            gemm(0, false, hbuf, 0, 0, 0, wek2 + (size_t)e * D * D, 0, ek_b2 + e * D, 0,
                 out_EO + e * D, E * D, 0, nullptr, 0, 0, Mtok, D, D, 1);
        }
    }

    // qk = sum_e mask * EO
    k_qk<<<dim3(4096), dim3(256), 0, stream>>>(out_EO, out_mask, qkb);

    // L2 = qa([qk | prompt | mL])  (fp32 out + bf16 copy)
    gemm(1, true, qkb, Pb, mLb, 0, wqa1, 0, qa_b1, 0, nullptr, 0, 0, hbuf, D, 0, Mtok, D, DIN, 1);
    gemm(0, false, hbuf, 0, 0, 0, wqa2, 0, qa_b2, 0, out_L2, D, 0, L2b, D, 0, Mtok, D, D, 1);

    // mL_pred = qc([mL | prompt | L2])
    gemm(1, true, mLb, Pb, L2b, 0, wqc1, 0, qc_b1, 0, nullptr, 0, 0, hbuf, D, 0, Mtok, D, DIN, 1);
    gemm(0, false, hbuf, 0, 0, 0, wqc2, 0, qc_b2, 0, out_mLp, D, 0, nullptr, 0, 0, Mtok, D, D, 1);

    // text_logits = L2 @ td_W + td_b
    gemm(0, false, L2b, 0, 0, 0, wtd, 0, td_b, 0, out_txt, V, 0, nullptr, 0, 0, Mtok, V, D, 1);
}

// Round 3
// 1545.061 us; speedup vs baseline: 1.1961x; 1.1961x over previous
//
#include <hip/hip_runtime.h>
#include <hip/hip_bf16.h>
#include <cstdint>
#include <cstddef>

using bf16 = __hip_bfloat16;

typedef __attribute__((ext_vector_type(4))) float f32x4;
typedef __attribute__((ext_vector_type(8))) short s16x8;

__device__ __forceinline__ bf16 to_bf16(float v) { return __float2bfloat16(v); }

struct alignas(8) bf16x4_pack { bf16 x, y, z, w; };

// bijective XCD-chunking swizzle (m204)
__device__ __forceinline__ int xcd_swz(int orig, int nwg) {
    int xcd = orig & 7, base = orig >> 3;
    int q = nwg >> 3, r = nwg & 7;
    return (xcd < r ? xcd * (q + 1) : r * (q + 1) + (xcd - r) * q) + base;
}

#define BAR()        asm volatile("s_barrier" ::: "memory")
#define WAITV4_BAR() asm volatile("s_waitcnt vmcnt(4)\ns_barrier" ::: "memory")
#define WAITV0_BAR() asm volatile("s_waitcnt vmcnt(0)\ns_barrier" ::: "memory")

// ---------------- fp32 -> bf16 elementwise ----------------
__global__ void k_conv_f32_bf16(const float* __restrict__ in, bf16* __restrict__ out, int n4) {
    int i = blockIdx.x * blockDim.x + threadIdx.x;
    if (i >= n4) return;
    float4 v = ((const float4*)in)[i];
    bf16x4_pack o{to_bf16(v.x), to_bf16(v.y), to_bf16(v.z), to_bf16(v.w)};
    ((bf16x4_pack*)out)[i] = o;
}

// ---------------- fp32 [K][N] -> bf16 [N][K] tiled transpose ----------------
__global__ __launch_bounds__(256) void k_transpose_f32_bf16(
    const float* __restrict__ in, bf16* __restrict__ out,
    int K, int N, long inz, long outz)
{
    __shared__ float t[32][33];
    in  += (long)blockIdx.z * inz;
    out += (long)blockIdx.z * outz;
    int n0 = blockIdx.x * 32, k0 = blockIdx.y * 32;
    int tx = threadIdx.x & 31, ty = threadIdx.x >> 5;
#pragma unroll
    for (int r = 0; r < 32; r += 8)
        t[ty + r][tx] = in[(long)(k0 + ty + r) * N + (n0 + tx)];
    __syncthreads();
#pragma unroll
    for (int r = 0; r < 32; r += 8)
        out[(long)(n0 + ty + r) * K + (k0 + tx)] = to_bf16(t[tx][ty + r]);
}

// ---------------- async global->LDS 16B helper ----------------
__device__ __forceinline__ void gload_lds16(const void* g, void* l) {
    __builtin_amdgcn_global_load_lds(
        (const __attribute__((address_space(1))) void*)g,
        (__attribute__((address_space(3))) void*)l,
        16, 0, 0);
}

// ================= 256x256 BK=64 8-wave phased GEMM (T2+T3+T4+T5) =================
// C = act(A[M,K] * W^T[N,K] + bias). 512 thr = 8 waves (2M x 4N), per-wave C 128x64.
// LDS 128KB: A/B x dbuf x [2 half][2 khalf][128 row][32 k] bf16, 8KB blocks.
// Swizzle: 16B-block index k16' = k16 ^ (row&3), applied on stage-source AND ds_read.
// Schedule per K-tile: 4 phases x {ds_read frags, 2x global_load_lds, bar, MFMA16, bar};
// counted vmcnt(4) at phase-1/phase-3 ends (vmcnt(0) only on last tile).
template<int ACT, int OUTF, int OUTB>   // ACT: 0 none, 1 relu, 2 silu
__global__ __launch_bounds__(512, 2) void k_gemm256(
    const bf16* __restrict__ A, int lda, long az,
    const bf16* __restrict__ W, long wz,
    const float* __restrict__ bias, long bz,
    float* __restrict__ Cf, int ldcf, long cfz,
    bf16* __restrict__ Cb, int ldcb, long cbz,
    int K, int nN)
{
    __shared__ char lds[131072];
    const int tid = threadIdx.x;
    const int wid = tid >> 6, lane = tid & 63;
    const int z = blockIdx.z;
    const int fid = xcd_swz(blockIdx.x, gridDim.x);
    const int m0 = (fid / nN) * 256;
    const int n0 = (fid % nN) * 256;
    const int wr = wid >> 2, wc = wid & 3;

    // stage source: thread t -> row t>>2 (0..127), 16B-block k16p = t&3 holds logical k16p^(row&3)
    const int srow = tid >> 2;
    const int sk   = ((tid & 3) ^ (srow & 3)) * 8;
    const bf16* Ag = A + (long)z * az + (long)(m0 + srow) * lda + sk;
    const bf16* Wg = W + (long)z * wz + (long)(n0 + srow) * K + sk;

    // reader byte offsets (within 128KB lds)
    const int fr = lane & 15;
    const int xorv = (((lane >> 4) ^ (lane & 3)) << 4);
    const int aRd = wr * 16384 + fr * 64 + xorv;                          // + db*32768 + kk*8192 + mi*1024
    const int bRd = 65536 + (wc >> 1) * 16384 + ((wc & 1) << 12) + fr * 64 + xorv; // + db*32768 + kk*8192 + ni*1024

    f32x4 acc[8][4] = {};
    const int NT = K >> 6;

    auto issueA = [&](int db, int kh, int kb) {
        char* l = lds + db * 32768 + kh * 8192 + wid * 1024;
        gload_lds16(Ag + kb + kh * 32, l);
        gload_lds16(Ag + kb + kh * 32 + (long)128 * lda, l + 16384);
    };
    auto issueB = [&](int db, int kh, int kb) {
        char* l = lds + 65536 + db * 32768 + kh * 8192 + wid * 1024;
        gload_lds16(Wg + kb + kh * 32, l);
        gload_lds16(Wg + kb + kh * 32 + (long)128 * K, l + 16384);
    };

    // prologue: tile 0 -> buf 0. Order matters for vmcnt counting: kh0 chunks first.
    issueA(0, 0, 0); issueB(0, 0, 0);
    issueA(0, 1, 0); issueB(0, 1, 0);
    WAITV4_BAR();     // oldest 4 = (t0, kh0) A+B landed

    for (int t = 0; t < NT; ++t) {
        const int db = t & 1, nb = db ^ 1;
        const int kn = (t + 1) << 6;
        const bool pf = (t + 1 < NT);
        const int abase = aRd + db * 32768;
        const int bbase = bRd + db * 32768;
        s16x8 a[4], b[4];

        // ---- phase 0: kk=0, mi 0-3 ----
#pragma unroll
        for (int i = 0; i < 4; ++i) b[i] = *(const s16x8*)(lds + bbase + i * 1024);
#pragma unroll
        for (int i = 0; i < 4; ++i) a[i] = *(const s16x8*)(lds + abase + i * 1024);
        if (pf) issueA(nb, 0, kn);
        BAR();
        __builtin_amdgcn_s_setprio(1);
#pragma unroll
        for (int mi = 0; mi < 4; ++mi)
#pragma unroll
            for (int ni = 0; ni < 4; ++ni)
                acc[mi][ni] = __builtin_amdgcn_mfma_f32_16x16x32_bf16(a[mi], b[ni], acc[mi][ni], 0, 0, 0);
        __builtin_amdgcn_s_setprio(0);
        BAR();

        // ---- phase 1: kk=0, mi 4-7 ----
#pragma unroll
        for (int i = 0; i < 4; ++i) a[i] = *(const s16x8*)(lds + abase + (4 + i) * 1024);
        if (pf) issueB(nb, 0, kn);
        BAR();
        __builtin_amdgcn_s_setprio(1);
#pragma unroll
        for (int mi = 0; mi < 4; ++mi)
#pragma unroll
            for (int ni = 0; ni < 4; ++ni)
                acc[4 + mi][ni] = __builtin_amdgcn_mfma_f32_16x16x32_bf16(a[mi], b[ni], acc[4 + mi][ni], 0, 0, 0);
        __builtin_amdgcn_s_setprio(0);
        if (pf) { WAITV4_BAR(); }    // oldest4 = (t, kh1) landed; (t+1, kh0) stays in flight
        else    { WAITV0_BAR(); }

        // ---- phase 2: kk=1, mi 0-3 ----
#pragma unroll
        for (int i = 0; i < 4; ++i) b[i] = *(const s16x8*)(lds + bbase + 8192 + i * 1024);
#pragma unroll
        for (int i = 0; i < 4; ++i) a[i] = *(const s16x8*)(lds + abase + 8192 + i * 1024);
        if (pf) issueA(nb, 1, kn);
        BAR();
        __builtin_amdgcn_s_setprio(1);
#pragma unroll
        for (int mi = 0; mi < 4; ++mi)
#pragma unroll
            for (int ni = 0; ni < 4; ++ni)
                acc[mi][ni] = __builtin_amdgcn_mfma_f32_16x16x32_bf16(a[mi], b[ni], acc[mi][ni], 0, 0, 0);
        __builtin_amdgcn_s_setprio(0);
        BAR();

        // ---- phase 3: kk=1, mi 4-7 ----
#pragma unroll
        for (int i = 0; i < 4; ++i) a[i] = *(const s16x8*)(lds + abase + 8192 + (4 + i) * 1024);
        if (pf) issueB(nb, 1, kn);
        BAR();
        __builtin_amdgcn_s_setprio(1);
#pragma unroll
        for (int mi = 0; mi < 4; ++mi)
#pragma unroll
            for (int ni = 0; ni < 4; ++ni)
                acc[4 + mi][ni] = __builtin_amdgcn_mfma_f32_16x16x32_bf16(a[mi], b[ni], acc[4 + mi][ni], 0, 0, 0);
        __builtin_amdgcn_s_setprio(0);
        if (pf) { WAITV4_BAR(); }    // oldest4 = (t+1, kh0) landed -> next tile phase 0 safe
        // last tile: fall through to epilogue (no LDS reads follow)
    }

    // epilogue: C/D layout col = lane&15, row = (lane>>4)*4 + r
    const int rb = (lane >> 4) * 4;
#pragma unroll
    for (int ni = 0; ni < 4; ++ni) {
        const int col = n0 + wc * 64 + ni * 16 + fr;
        const float bv = bias[(long)z * bz + col];
#pragma unroll
        for (int mi = 0; mi < 8; ++mi) {
#pragma unroll
            for (int r = 0; r < 4; ++r) {
                const int row = m0 + wr * 128 + mi * 16 + rb + r;
                float v = acc[mi][ni][r] + bv;
                if (ACT == 1) v = fmaxf(v, 0.f);
                if (ACT == 2) v = v / (1.f + __expf(-v));
                if (OUTF) Cf[(long)z * cfz + (long)row * ldcf + col] = v;
                if (OUTB) Cb[(long)z * cbz + (long)row * ldcb + col] = to_bf16(v);
            }
        }
    }
}

// ================= 128x128 m97-style GEMM (kept for N=1024 / K=3072 shapes) =================
template<int ACT, int SEG>
__global__ __launch_bounds__(256) void k_gemm(
    const bf16* __restrict__ A0, const bf16* __restrict__ A1, const bf16* __restrict__ A2,
    long az,
    const bf16* __restrict__ W, long wz,
    const float* __restrict__ bias, long bz,
    float* __restrict__ Cf, int ldcf, long cfz,
    bf16* __restrict__ Cb, int ldcb, long cbz,
    int K, int nM)
{
    __shared__ bf16 As[128 * 32];
    __shared__ bf16 Bs[128 * 32];
    const int tid  = threadIdx.x;
    const int wid  = tid >> 6;
    const int lane = tid & 63;
    const int z  = blockIdx.z;

    const int fid = xcd_swz(blockIdx.x, gridDim.x);
    const int m0 = (fid % nM) * 128;
    const int n0 = (fid / nM) * 128;

    const int srow = tid >> 2;
    const int scol = (tid & 3) * 8;
    const long arow = (long)(m0 + srow) * 1024 + scol;
    const bf16* a0 = A0 + (long)z * az + arow;
    const bf16* a1 = SEG ? (A1 + arow) : nullptr;
    const bf16* a2 = SEG ? (A2 + arow) : nullptr;
    const bf16* bg = W + (long)z * wz + (long)(n0 + srow) * K + scol;

    char* asb = (char*)As;
    char* bsb = (char*)Bs;

    f32x4 acc[4][4] = {};

    const int wm = (wid >> 1) * 64;
    const int wn = (wid & 1) * 64;
    const int fr = lane & 15;
    const int kq = (lane >> 4) * 8;

    for (int k0 = 0; k0 < K; k0 += 32) {
        const bf16* ap;
        if (SEG) {
            const int seg = k0 >> 10, ko = k0 & 1023;
            ap = (seg == 0 ? a0 : (seg == 1 ? a1 : a2)) + ko;
        } else {
            ap = a0 + k0;
        }
        const bf16* bp = bg + k0;

        __syncthreads();
        gload_lds16(ap,                 asb + wid * 1024);
        gload_lds16(ap + 64 * 1024,     asb + 4096 + wid * 1024);
        gload_lds16(bp,                 bsb + wid * 1024);
        gload_lds16(bp + (long)64 * K,  bsb + 4096 + wid * 1024);
        __syncthreads();

        s16x8 af[4], bfv[4];
#pragma unroll
        for (int i = 0; i < 4; ++i)
            af[i] = *(const s16x8*)(As + (wm + i * 16 + fr) * 32 + kq);
#pragma unroll
        for (int i = 0; i < 4; ++i)
            bfv[i] = *(const s16x8*)(Bs + (wn + i * 16 + fr) * 32 + kq);
#pragma unroll
        for (int mi = 0; mi < 4; ++mi)
#pragma unroll
            for (int ni = 0; ni < 4; ++ni)
                acc[mi][ni] = __builtin_amdgcn_mfma_f32_16x16x32_bf16(
                    af[mi], bfv[ni], acc[mi][ni], 0, 0, 0);
    }

    const int rb = (lane >> 4) * 4;
#pragma unroll
    for (int ni = 0; ni < 4; ++ni) {
        const int col = n0 + wn + ni * 16 + fr;
        const float bv = bias ? bias[(long)z * bz + col] : 0.f;
#pragma unroll
        for (int mi = 0; mi < 4; ++mi) {
#pragma unroll
            for (int r = 0; r < 4; ++r) {
                const int row = m0 + wm + mi * 16 + rb + r;
                float v = acc[mi][ni][r] + bv;
                if (ACT == 1) v = fmaxf(v, 0.f);
                if (ACT == 2) v = v / (1.f + __expf(-v));
                if (Cf) Cf[(long)z * cfz + (long)row * ldcf + col] = v;
                if (Cb) Cb[(long)z * cbz + (long)row * ldcb + col] = to_bf16(v);
            }
        }
    }
}

// ---------------- fused mask head ----------------
__global__ __launch_bounds__(64) void k_mask_softmax(
    const bf16* __restrict__ t, const float* __restrict__ W2,
    const float* __restrict__ b2, float* __restrict__ mask_out)
{
    const int tok = blockIdx.x;
    const int lane = threadIdx.x;
    float part[16];
#pragma unroll
    for (int e = 0; e < 16; ++e) part[e] = 0.f;
    const bf16* tr = t + (long)tok * 1024 + lane * 16;
#pragma unroll
    for (int kk = 0; kk < 16; ++kk) {
        float x = __bfloat162float(tr[kk]);
        const float* wr = W2 + (long)(lane * 16 + kk) * 16;
#pragma unroll
        for (int e = 0; e < 16; ++e) part[e] += x * wr[e];
    }
#pragma unroll
    for (int e = 0; e < 16; ++e) {
#pragma unroll
        for (int off = 32; off >= 1; off >>= 1)
            part[e] += __shfl_down(part[e], off);
    }
    if (lane == 0) {
        float vals[16], mx = -1e30f;
#pragma unroll
        for (int e = 0; e < 16; ++e) { vals[e] = part[e] + b2[e]; mx = fmaxf(mx, vals[e]); }
        float s = 0.f;
#pragma unroll
        for (int e = 0; e < 16; ++e) { vals[e] = __expf(vals[e] - mx); s += vals[e]; }
        float inv = 1.f / s;
#pragma unroll
        for (int e = 0; e < 16; ++e) mask_out[tok * 16 + e] = vals[e] * inv;
    }
}

// ---------------- qk = sum_e mask[tok][e] * EO[tok][e][:] -> bf16 ----------------
__global__ void k_qk(const float* __restrict__ EO, const float* __restrict__ mask,
                     bf16* __restrict__ qkb)
{
    int i = blockIdx.x * blockDim.x + threadIdx.x;
    int tok = i >> 8;
    int d4  = (i & 255) << 2;
    const float* eo = EO + (long)tok * 16384 + d4;
    const float* mk = mask + tok * 16;
    float4 s = make_float4(0.f, 0.f, 0.f, 0.f);
#pragma unroll
    for (int e = 0; e < 16; ++e) {
        float m = mk[e];
        float4 v = *(const float4*)(eo + e * 1024);
        s.x += m * v.x; s.y += m * v.y; s.z += m * v.z; s.w += m * v.w;
    }
    bf16x4_pack o{to_bf16(s.x), to_bf16(s.y), to_bf16(s.z), to_bf16(s.w)};
    ((bf16x4_pack*)qkb)[i] = o;
}

extern "C" void kernel_launch(void* const* d_in, const int* in_sizes, int n_in,
                              void* d_out, int out_size, void* d_ws, size_t ws_size,
                              hipStream_t stream)
{
    const int Mtok = 4096, D = 1024, E = 16, V = 32000, DIN = 3072;

    const float* L      = (const float*)d_in[0];
    const float* mL     = (const float*)d_in[1];
    const float* prompt = (const float*)d_in[2];
    const float* noise  = (const float*)d_in[3];
    const float* qa_W1 = (const float*)d_in[4];  const float* qa_b1 = (const float*)d_in[5];
    const float* qa_W2 = (const float*)d_in[6];  const float* qa_b2 = (const float*)d_in[7];
    const float* qb_W1 = (const float*)d_in[8];  const float* qb_b1 = (const float*)d_in[9];
    const float* qb_W2 = (const float*)d_in[10]; const float* qb_b2 = (const float*)d_in[11];
    const float* qc_W1 = (const float*)d_in[12]; const float* qc_b1 = (const float*)d_in[13];
    const float* qc_W2 = (const float*)d_in[14]; const float* qc_b2 = (const float*)d_in[15];
    const float* ek_W1 = (const float*)d_in[16]; const float* ek_b1 = (const float*)d_in[17];
    const float* ek_W2 = (const float*)d_in[18]; const float* ek_b2 = (const float*)d_in[19];
    const float* md_W1 = (const float*)d_in[20]; const float* md_b1 = (const float*)d_in[21];
    const float* md_W2 = (const float*)d_in[22]; const float* md_b2 = (const float*)d_in[23];
    const float* td_W  = (const float*)d_in[24]; const float* td_b  = (const float*)d_in[25];

    float* out = (float*)d_out;
    float* out_L2   = out;
    float* out_mLp  = out + 4194304;
    float* out_mask = out + 8388608;
    float* out_txt  = out + 8454144;
    float* out_EO   = out + 139526144;

    char* ws = (char*)d_ws;
    size_t off = 0;
    auto alloc = [&](size_t bytes) -> void* {
        void* p = ws + off;
        off += (bytes + 255) & ~(size_t)255;
        return p;
    };

    bf16* wqa1 = (bf16*)alloc((size_t)DIN * D * 2);
    bf16* wqa2 = (bf16*)alloc((size_t)D * D * 2);
    bf16* wqb1 = (bf16*)alloc((size_t)DIN * D * 2);
    bf16* wqb2 = (bf16*)alloc((size_t)D * D * 2);
    bf16* wqc1 = (bf16*)alloc((size_t)DIN * D * 2);
    bf16* wqc2 = (bf16*)alloc((size_t)D * D * 2);
    bf16* wmd1 = (bf16*)alloc((size_t)D * D * 2);
    bf16* wek1 = (bf16*)alloc((size_t)E * D * D * 2);
    bf16* wek2 = (bf16*)alloc((size_t)E * D * D * 2);
    bf16* wtd  = (bf16*)alloc((size_t)D * V * 2);

    bf16* Lb   = (bf16*)alloc((size_t)Mtok * D * 2);
    bf16* mLb  = (bf16*)alloc((size_t)Mtok * D * 2);
    bf16* Pb   = (bf16*)alloc((size_t)Mtok * D * 2);
    bf16* Nb   = (bf16*)alloc((size_t)Mtok * D * 2);
    bf16* hbuf = (bf16*)alloc((size_t)Mtok * D * 2);
    bf16* L1b  = (bf16*)alloc((size_t)Mtok * D * 2);
    bf16* sLb  = (bf16*)alloc((size_t)Mtok * D * 2);
    bf16* tb   = (bf16*)alloc((size_t)Mtok * D * 2);
    bf16* qkb  = (bf16*)alloc((size_t)Mtok * D * 2);
    bf16* L2b  = (bf16*)alloc((size_t)Mtok * D * 2);

    const size_t hall_bytes = (size_t)E * Mtok * D * 2;
    bool batched = (off + hall_bytes + 256 <= ws_size);
    bf16* hall = batched ? (bf16*)alloc(hall_bytes) : nullptr;

    auto conv = [&](const float* src, bf16* dst, long n) {
        int n4 = (int)(n / 4);
        k_conv_f32_bf16<<<dim3((n4 + 255) / 256), dim3(256), 0, stream>>>(src, dst, n4);
    };
    conv(L, Lb, (long)Mtok * D);
    conv(mL, mLb, (long)Mtok * D);
    conv(prompt, Pb, (long)Mtok * D);
    conv(noise, Nb, (long)Mtok * D);

    auto transp = [&](const float* src, bf16* dst, int K, int N, int Z, long inz, long outz) {
        dim3 g(N / 32, K / 32, Z);
        k_transpose_f32_bf16<<<g, dim3(256), 0, stream>>>(src, dst, K, N, inz, outz);
    };
    transp(qa_W1, wqa1, DIN, D, 1, 0, 0);
    transp(qa_W2, wqa2, D, D, 1, 0, 0);
    transp(qb_W1, wqb1, DIN, D, 1, 0, 0);
    transp(qb_W2, wqb2, D, D, 1, 0, 0);
    transp(qc_W1, wqc1, DIN, D, 1, 0, 0);
    transp(qc_W2, wqc2, D, D, 1, 0, 0);
    transp(md_W1, wmd1, D, D, 1, 0, 0);
    transp(ek_W1, wek1, D, D, 16, (long)D * D, (long)D * D);
    transp(ek_W2, wek2, D, D, 16, (long)D * D, (long)D * D);
    transp(td_W,  wtd,  D, V, 1, 0, 0);

    auto gemm = [&](int ACT, bool seg,
                    const bf16* A0, const bf16* A1, const bf16* A2, long az,
                    const bf16* Wt, long wz, const float* bias, long bz,
                    float* Cf, int ldcf, long cfz, bf16* Cb, int ldcb, long cbz,
                    int M, int N, int K, int Z) {
        int nM = M / 128, nN = N / 128;
        dim3 g(nM * nN, 1, Z);
        dim3 b(256);
        if (seg) {
            if (ACT == 1)
                k_gemm<1, 1><<<g, b, 0, stream>>>(A0, A1, A2, az, Wt, wz, bias, bz, Cf, ldcf, cfz, Cb, ldcb, cbz, K, nM);
            else
                k_gemm<0, 1><<<g, b, 0, stream>>>(A0, A1, A2, az, Wt, wz, bias, bz, Cf, ldcf, cfz, Cb, ldcb, cbz, K, nM);
        } else {
            if (ACT == 0)
                k_gemm<0, 0><<<g, b, 0, stream>>>(A0, A0, A0, az, Wt, wz, bias, bz, Cf, ldcf, cfz, Cb, ldcb, cbz, K, nM);
            else if (ACT == 1)
                k_gemm<1, 0><<<g, b, 0, stream>>>(A0, A0, A0, az, Wt, wz, bias, bz, Cf, ldcf, cfz, Cb, ldcb, cbz, K, nM);
            else
                k_gemm<2, 0><<<g, b, 0, stream>>>(A0, A0, A0, az, Wt, wz, bias, bz, Cf, ldcf, cfz, Cb, ldcb, cbz, K, nM);
        }
    };

    // L1 = qa([L | prompt | mL])
    gemm(1, true, Lb, Pb, mLb, 0, wqa1, 0, qa_b1, 0, nullptr, 0, 0, hbuf, D, 0, Mtok, D, DIN, 1);
    gemm(0, false, hbuf, 0, 0, 0, wqa2, 0, qa_b2, 0, nullptr, 0, 0, L1b, D, 0, Mtok, D, D, 1);

    // sL = qb([noise | prompt | L1])
    gemm(1, true, Nb, Pb, L1b, 0, wqb1, 0, qb_b1, 0, nullptr, 0, 0, hbuf, D, 0, Mtok, D, DIN, 1);
    gemm(0, false, hbuf, 0, 0, 0, wqb2, 0, qb_b2, 0, nullptr, 0, 0, sLb, D, 0, Mtok, D, D, 1);

    // mask = softmax(relu(sL @ md_W1 + b1) @ md_W2 + b2)
    gemm(1, false, sLb, 0, 0, 0, wmd1, 0, md_b1, 0, nullptr, 0, 0, tb, D, 0, Mtok, D, D, 1);
    k_mask_softmax<<<dim3(Mtok), dim3(64), 0, stream>>>(tb, md_W2, md_b2, out_mask);

    // experts via 256^2 phased kernel (z=16): h = silu(L1@W1+b1); EO = h@W2+b2
    if (batched) {
        dim3 ge(16 * 4, 1, 16), be(512);
        k_gemm256<2, 0, 1><<<ge, be, 0, stream>>>(
            L1b, D, 0, wek1, (long)D * D, ek_b1, D,
            nullptr, 0, 0, hall, D, (long)Mtok * D, D, 4);
        k_gemm256<0, 1, 0><<<ge, be, 0, stream>>>(
            hall, D, (long)Mtok * D, wek2, (long)D * D, ek_b2, D,
            out_EO, E * D, D, nullptr, 0, 0, D, 4);
    } else {
        for (int e = 0; e < 16; ++e) {
            gemm(2, false, L1b, 0, 0, 0, wek1 + (size_t)e * D * D, 0, ek_b1 + e * D, 0,
                 nullptr, 0, 0, hbuf, D, 0, Mtok, D, D, 1);
            gemm(0, false, hbuf, 0, 0, 0, wek2 + (size_t)e * D * D, 0, ek_b2 + e * D, 0,
                 out_EO + e * D, E * D, 0, nullptr, 0, 0, Mtok, D, D, 1);
        }
    }

    // qk = sum_e mask * EO
    k_qk<<<dim3(4096), dim3(256), 0, stream>>>(out_EO, out_mask, qkb);

    // L2 = qa([qk | prompt | mL])
    gemm(1, true, qkb, Pb, mLb, 0, wqa1, 0, qa_b1, 0, nullptr, 0, 0, hbuf, D, 0, Mtok, D, DIN, 1);
    gemm(0, false, hbuf, 0, 0, 0, wqa2, 0, qa_b2, 0, out_L2, D, 0, L2b, D, 0, Mtok, D, D, 1);

    // mL_pred = qc([mL | prompt | L2])
    gemm(1, true, mLb, Pb, L2b, 0, wqc1, 0, qc_b1, 0, nullptr, 0, 0, hbuf, D, 0, Mtok, D, DIN, 1);
    gemm(0, false, hbuf, 0, 0, 0, wqc2, 0, qc_b2, 0, out_mLp, D, 0, nullptr, 0, 0, Mtok, D, D, 1);

    // text_logits = L2 @ td_W + td_b  (256^2 phased kernel)
    {
        dim3 gl(16 * 125, 1, 1), bl(512);
        k_gemm256<0, 1, 0><<<gl, bl, 0, stream>>>(
            L2b, D, 0, wtd, 0, td_b, 0,
            out_txt, V, 0, nullptr, 0, 0, D, 125);
    }
}